// Round 2
// baseline (233.814 us; speedup 1.0000x reference)
//
#include <hip/hip_runtime.h>

// Problem constants (match reference)
#define Bq 8
#define Cq 128
#define Hq 128
#define Wq 256
#define Nq 1024
#define BN (Bq * Nq)
#define HWq (Hq * Wq)            // 32768 pixels per (b,c) plane
#define FBT_ELEMS ((size_t)Bq * Cq * HWq)   // 33,554,432 floats = 128 MiB

#define LOG_2PI 1.8378770664093453f
#define EPSq 1e-9f

// ---------------------------------------------------------------------------
// Pass 1: NCHW -> NHWC transpose.  Per batch b, this is a 2D transpose of a
// (C=128) x (HW=32768) matrix.  64x64 LDS tile, +1 pad, both sides coalesced.
// Grid: B * (HW/64) * (C/64) = 8 * 512 * 2 = 8192 blocks of 256 threads.
// ---------------------------------------------------------------------------
__global__ __launch_bounds__(256) void transpose_nchw_nhwc(
    const float* __restrict__ in, float* __restrict__ out)
{
    __shared__ float tile[64][65];
    const int blk = blockIdx.x;
    const int ct = blk & 1;            // c-tile (0..1)
    const int pt = (blk >> 1) & 511;   // p-tile (0..511)
    const int b  = blk >> 10;          // batch  (0..7)
    const int c0 = ct << 6;
    const int p0 = pt << 6;
    const int tx = threadIdx.x & 63;
    const int ty = threadIdx.x >> 6;   // 0..3

    const float* src = in + ((size_t)b * Cq + c0) * HWq + p0;
    #pragma unroll
    for (int i = 0; i < 16; ++i) {
        const int cy = ty + (i << 2);
        tile[cy][tx] = src[(size_t)cy * HWq + tx];   // coalesced read along p
    }
    __syncthreads();
    float* dst = out + ((size_t)b * HWq + p0) * Cq + c0;
    #pragma unroll
    for (int i = 0; i < 16; ++i) {
        const int py = ty + (i << 2);
        dst[(size_t)py * Cq + tx] = tile[tx][py];    // coalesced write along c
    }
}

// ---------------------------------------------------------------------------
// Pass 2: per-sample Gauss-Newton accumulation on NHWC data.
// One 64-lane wave per sample; each lane owns channels (2*lane, 2*lane+1) via
// float2 loads -> every stencil-point load is a contiguous 512B wave fetch.
// ---------------------------------------------------------------------------
__global__ __launch_bounds__(64) void gn_sample_nhwc(
    const float* __restrict__ fbT,
    const float* __restrict__ f_t,
    const float* __restrict__ ub,
    const float* __restrict__ noise,
    float* __restrict__ partials)
{
    const int n = blockIdx.x;          // sample index in [0, B*N)
    const int b = n >> 10;             // n / N  (N = 1024)
    const int lane = threadIdx.x;      // 0..63

    const float ubx = ub[2 * n];
    const float uby = ub[2 * n + 1];
    const float xsx = ubx + noise[2 * n];
    const float xsy = uby + noise[2 * n + 1];

    float x = fminf(fmaxf(xsx, 0.0f), (float)(Wq - 1));
    float y = fminf(fmaxf(xsy, 0.0f), (float)(Hq - 1));
    int x0 = (int)floorf(x); x0 = min(max(x0, 0), Wq - 2);
    int y0 = (int)floorf(y); y0 = min(max(y0, 0), Hq - 2);
    const int x1 = x0 + 1, y1 = y0 + 1;
    const float wx = x - (float)x0;
    const float wy = y - (float)y0;

    const int xlo0 = max(x0 - 1, 0);
    const int xhi1 = min(x1 + 1, Wq - 1);
    const int ylo0 = max(y0 - 1, 0);
    const int yhi1 = min(y1 + 1, Hq - 1);
    const float sx0 = 1.0f / (float)(x1 - xlo0);
    const float sx1 = 1.0f / (float)(xhi1 - x0);
    const float sy0 = 1.0f / (float)(y1 - ylo0);
    const float sy1 = 1.0f / (float)(yhi1 - y0);

    // NHWC base for this batch; point (yy, xx) -> contiguous C run
    const size_t bb = (size_t)b * HWq;
    const int co = lane * 2;
    #define PT(yy, xx) (*(const float2*)(fbT + ((bb + (size_t)(yy) * Wq + (xx)) * Cq + co)))

    const float2 f_lo0 = PT(ylo0, x0), f_lo1 = PT(ylo0, x1);
    const float2 f0m = PT(y0, xlo0), f00 = PT(y0, x0), f01 = PT(y0, x1), f0p = PT(y0, xhi1);
    const float2 f1m = PT(y1, xlo0), f10 = PT(y1, x0), f11 = PT(y1, x1), f1p = PT(y1, xhi1);
    const float2 f_hi0 = PT(yhi1, x0), f_hi1 = PT(yhi1, x1);
    #undef PT

    const float2 ft = *(const float2*)(f_t + (size_t)n * Cq + co);

    const float w00 = (1.0f - wx) * (1.0f - wy);
    const float w01 = wx * (1.0f - wy);
    const float w10 = (1.0f - wx) * wy;
    const float w11 = wx * wy;

    float hxx = 0.0f, hxy = 0.0f, hyy = 0.0f, bx = 0.0f, by = 0.0f;
    #pragma unroll
    for (int k = 0; k < 2; ++k) {
        const float vlo0 = (k ? f_lo0.y : f_lo0.x), vlo1 = (k ? f_lo1.y : f_lo1.x);
        const float v0m = (k ? f0m.y : f0m.x), v00 = (k ? f00.y : f00.x);
        const float v01 = (k ? f01.y : f01.x), v0p = (k ? f0p.y : f0p.x);
        const float v1m = (k ? f1m.y : f1m.x), v10 = (k ? f10.y : f10.x);
        const float v11 = (k ? f11.y : f11.x), v1p = (k ? f1p.y : f1p.x);
        const float vhi0 = (k ? f_hi0.y : f_hi0.x), vhi1 = (k ? f_hi1.y : f_hi1.x);
        const float vt = (k ? ft.y : ft.x);

        const float gx00 = (v01 - v0m) * sx0;
        const float gx01 = (v0p - v00) * sx1;
        const float gx10 = (v11 - v1m) * sx0;
        const float gx11 = (v1p - v10) * sx1;
        const float gy00 = (v10 - vlo0) * sy0;
        const float gy01 = (v11 - vlo1) * sy0;
        const float gy10 = (vhi0 - v00) * sy1;
        const float gy11 = (vhi1 - v01) * sy1;

        const float fs = v00 * w00 + v01 * w01 + v10 * w10 + v11 * w11;
        const float Jx = gx00 * w00 + gx01 * w01 + gx10 * w10 + gx11 * w11;
        const float Jy = gy00 * w00 + gy01 * w01 + gy10 * w10 + gy11 * w11;
        const float r  = fs - vt;

        hxx += Jx * Jx;
        hxy += Jx * Jy;
        hyy += Jy * Jy;
        bx  += Jx * r;
        by  += Jy * r;
    }

    // 64-lane wave reduction (no LDS needed)
    #pragma unroll
    for (int off = 32; off > 0; off >>= 1) {
        hxx += __shfl_down(hxx, off);
        hxy += __shfl_down(hxy, off);
        hyy += __shfl_down(hyy, off);
        bx  += __shfl_down(bx, off);
        by  += __shfl_down(by, off);
    }

    if (lane == 0) {
        const float A  = hxx + EPSq;
        const float Bv = hxy;
        const float D  = hyy + EPSq;

        const float det = A * D - Bv * Bv;
        const float inv = 1.0f / det;
        const float hbx = ( D * bx - Bv * by) * inv;
        const float hby = (-Bv * bx + A * by) * inv;
        const float dx = ubx - (xsx - hbx);
        const float dy = uby - (xsy - hby);
        const float quad = A * dx * dx + 2.0f * Bv * dx * dy + D * dy * dy;

        const float detc = fmaxf(det, 1e-16f);
        partials[n]      = 0.5f * quad;     // e1 contribution
        partials[BN + n] = logf(detc);      // log det contribution
    }
}

// ---------------------------------------------------------------------------
// Single-block final reduction -> (e, e1, e2)
// ---------------------------------------------------------------------------
__global__ __launch_bounds__(1024) void gn_reduce_kernel(
    const float* __restrict__ partials, float* __restrict__ out)
{
    float s1 = 0.0f, s2 = 0.0f;
    for (int i = threadIdx.x; i < BN; i += 1024) {
        s1 += partials[i];
        s2 += partials[BN + i];
    }
    #pragma unroll
    for (int off = 32; off > 0; off >>= 1) {
        s1 += __shfl_down(s1, off);
        s2 += __shfl_down(s2, off);
    }
    __shared__ float l1[16], l2[16];
    const int w = threadIdx.x >> 6;
    if ((threadIdx.x & 63) == 0) { l1[w] = s1; l2[w] = s2; }
    __syncthreads();
    if (threadIdx.x == 0) {
        float e1 = 0.0f, sl = 0.0f;
        #pragma unroll
        for (int i = 0; i < 16; ++i) { e1 += l1[i]; sl += l2[i]; }
        const float e2 = (float)BN * LOG_2PI - 0.5f * sl;
        out[0] = e1 + (2.0f / 7.0f) * e2;  // e
        out[1] = e1;
        out[2] = e2;
    }
}

extern "C" void kernel_launch(void* const* d_in, const int* in_sizes, int n_in,
                              void* d_out, int out_size, void* d_ws, size_t ws_size,
                              hipStream_t stream) {
    const float* fb    = (const float*)d_in[0];
    const float* f_t   = (const float*)d_in[1];
    const float* ub    = (const float*)d_in[2];
    const float* noise = (const float*)d_in[3];
    float* out = (float*)d_out;
    float* wsf = (float*)d_ws;
    float* fbT      = wsf;                 // 128 MiB NHWC copy of fb
    float* partials = wsf + FBT_ELEMS;     // 2 * B*N floats

    transpose_nchw_nhwc<<<Bq * (HWq / 64) * (Cq / 64), 256, 0, stream>>>(fb, fbT);
    gn_sample_nhwc<<<BN, 64, 0, stream>>>(fbT, f_t, ub, noise, partials);
    gn_reduce_kernel<<<1, 1024, 0, stream>>>(partials, out);
}

// Round 3
// 233.298 us; speedup vs baseline: 1.0022x; 1.0022x over previous
//
#include <hip/hip_runtime.h>

// Problem constants (match reference)
#define Bq 8
#define Cq 128
#define Hq 128
#define Wq 256
#define Nq 1024
#define BN (Bq * Nq)
#define HWq (Hq * Wq)            // 32768 pixels per (b,c) plane
#define FBT_ELEMS ((size_t)Bq * Cq * HWq)   // 33,554,432 floats = 128 MiB

#define LOG_2PI 1.8378770664093453f
#define EPSq 1e-9f

// ---------------------------------------------------------------------------
// Pass 1: NCHW -> NHWC transpose, float4 on BOTH global sides.
// Per batch b this is a (C=128) x (HW=32768) transpose. 64x64 tile.
// LDS tile[64][65] scalar; banks: write (r + 4fx + i)%32 -> 2-way max (free),
// read (4c4 + j + p)%32 -> 2-way max (free).
// Grid: B * (HW/64) * (C/64) = 8192 blocks of 256 threads.
// ---------------------------------------------------------------------------
__global__ __launch_bounds__(256) void transpose_nchw_nhwc(
    const float* __restrict__ in, float* __restrict__ out)
{
    __shared__ float tile[64][65];
    const int blk = blockIdx.x;
    const int ct = blk & 1;            // c-tile (0..1)
    const int pt = (blk >> 1) & 511;   // p-tile (0..511)
    const int b  = blk >> 10;          // batch  (0..7)
    const int c0 = ct << 6;
    const int p0 = pt << 6;
    const int fx = threadIdx.x & 15;   // float4 index within a 64-float row
    const int rr = threadIdx.x >> 4;   // 0..15

    const float* src = in + ((size_t)b * Cq + c0) * HWq + p0;
    #pragma unroll
    for (int it = 0; it < 4; ++it) {
        const int r = rr + (it << 4);                    // c-row 0..63
        const float4 v = *(const float4*)(src + (size_t)r * HWq + 4 * fx);
        tile[r][4 * fx + 0] = v.x;
        tile[r][4 * fx + 1] = v.y;
        tile[r][4 * fx + 2] = v.z;
        tile[r][4 * fx + 3] = v.w;
    }
    __syncthreads();
    float* dst = out + ((size_t)b * HWq + p0) * Cq + c0;
    #pragma unroll
    for (int it = 0; it < 4; ++it) {
        const int p = rr + (it << 4);                    // p-row 0..63
        float4 v;
        v.x = tile[4 * fx + 0][p];
        v.y = tile[4 * fx + 1][p];
        v.z = tile[4 * fx + 2][p];
        v.w = tile[4 * fx + 3][p];
        *(float4*)(dst + (size_t)p * Cq + 4 * fx) = v;
    }
}

// ---------------------------------------------------------------------------
// Pass 2: per-sample Gauss-Newton accumulation on NHWC data.
// 4 samples per 256-thread block; each sample owned by one 64-lane wave.
// Lane owns channels (2*lane, 2*lane+1) via float2 -> every stencil-point
// load is one contiguous 512B wave fetch. Pure wave reduction, no LDS.
// ---------------------------------------------------------------------------
__global__ __launch_bounds__(256) void gn_sample_nhwc(
    const float* __restrict__ fbT,
    const float* __restrict__ f_t,
    const float* __restrict__ ub,
    const float* __restrict__ noise,
    float* __restrict__ partials)
{
    const int n = (blockIdx.x << 2) + (threadIdx.x >> 6);  // sample in [0, B*N)
    const int b = n >> 10;             // n / N  (N = 1024)
    const int lane = threadIdx.x & 63;

    const float ubx = ub[2 * n];
    const float uby = ub[2 * n + 1];
    const float xsx = ubx + noise[2 * n];
    const float xsy = uby + noise[2 * n + 1];

    float x = fminf(fmaxf(xsx, 0.0f), (float)(Wq - 1));
    float y = fminf(fmaxf(xsy, 0.0f), (float)(Hq - 1));
    int x0 = (int)floorf(x); x0 = min(max(x0, 0), Wq - 2);
    int y0 = (int)floorf(y); y0 = min(max(y0, 0), Hq - 2);
    const int x1 = x0 + 1, y1 = y0 + 1;
    const float wx = x - (float)x0;
    const float wy = y - (float)y0;

    const int xlo0 = max(x0 - 1, 0);
    const int xhi1 = min(x1 + 1, Wq - 1);
    const int ylo0 = max(y0 - 1, 0);
    const int yhi1 = min(y1 + 1, Hq - 1);
    const float sx0 = 1.0f / (float)(x1 - xlo0);
    const float sx1 = 1.0f / (float)(xhi1 - x0);
    const float sy0 = 1.0f / (float)(y1 - ylo0);
    const float sy1 = 1.0f / (float)(yhi1 - y0);

    const size_t bb = (size_t)b * HWq;
    const int co = lane * 2;
    #define PT(yy, xx) (*(const float2*)(fbT + ((bb + (size_t)(yy) * Wq + (xx)) * Cq + co)))

    const float2 f_lo0 = PT(ylo0, x0), f_lo1 = PT(ylo0, x1);
    const float2 f0m = PT(y0, xlo0), f00 = PT(y0, x0), f01 = PT(y0, x1), f0p = PT(y0, xhi1);
    const float2 f1m = PT(y1, xlo0), f10 = PT(y1, x0), f11 = PT(y1, x1), f1p = PT(y1, xhi1);
    const float2 f_hi0 = PT(yhi1, x0), f_hi1 = PT(yhi1, x1);
    #undef PT

    const float2 ft = *(const float2*)(f_t + (size_t)n * Cq + co);

    const float w00 = (1.0f - wx) * (1.0f - wy);
    const float w01 = wx * (1.0f - wy);
    const float w10 = (1.0f - wx) * wy;
    const float w11 = wx * wy;

    float hxx = 0.0f, hxy = 0.0f, hyy = 0.0f, bx = 0.0f, by = 0.0f;
    #pragma unroll
    for (int k = 0; k < 2; ++k) {
        const float vlo0 = (k ? f_lo0.y : f_lo0.x), vlo1 = (k ? f_lo1.y : f_lo1.x);
        const float v0m = (k ? f0m.y : f0m.x), v00 = (k ? f00.y : f00.x);
        const float v01 = (k ? f01.y : f01.x), v0p = (k ? f0p.y : f0p.x);
        const float v1m = (k ? f1m.y : f1m.x), v10 = (k ? f10.y : f10.x);
        const float v11 = (k ? f11.y : f11.x), v1p = (k ? f1p.y : f1p.x);
        const float vhi0 = (k ? f_hi0.y : f_hi0.x), vhi1 = (k ? f_hi1.y : f_hi1.x);
        const float vt = (k ? ft.y : ft.x);

        const float gx00 = (v01 - v0m) * sx0;
        const float gx01 = (v0p - v00) * sx1;
        const float gx10 = (v11 - v1m) * sx0;
        const float gx11 = (v1p - v10) * sx1;
        const float gy00 = (v10 - vlo0) * sy0;
        const float gy01 = (v11 - vlo1) * sy0;
        const float gy10 = (vhi0 - v00) * sy1;
        const float gy11 = (vhi1 - v01) * sy1;

        const float fs = v00 * w00 + v01 * w01 + v10 * w10 + v11 * w11;
        const float Jx = gx00 * w00 + gx01 * w01 + gx10 * w10 + gx11 * w11;
        const float Jy = gy00 * w00 + gy01 * w01 + gy10 * w10 + gy11 * w11;
        const float r  = fs - vt;

        hxx += Jx * Jx;
        hxy += Jx * Jy;
        hyy += Jy * Jy;
        bx  += Jx * r;
        by  += Jy * r;
    }

    // 64-lane wave reduction (stays inside each wave; no LDS, no sync)
    #pragma unroll
    for (int off = 32; off > 0; off >>= 1) {
        hxx += __shfl_down(hxx, off);
        hxy += __shfl_down(hxy, off);
        hyy += __shfl_down(hyy, off);
        bx  += __shfl_down(bx, off);
        by  += __shfl_down(by, off);
    }

    if (lane == 0) {
        const float A  = hxx + EPSq;
        const float Bv = hxy;
        const float D  = hyy + EPSq;

        const float det = A * D - Bv * Bv;
        const float inv = 1.0f / det;
        const float hbx = ( D * bx - Bv * by) * inv;
        const float hby = (-Bv * bx + A * by) * inv;
        const float dx = ubx - (xsx - hbx);
        const float dy = uby - (xsy - hby);
        const float quad = A * dx * dx + 2.0f * Bv * dx * dy + D * dy * dy;

        const float detc = fmaxf(det, 1e-16f);
        partials[n]      = 0.5f * quad;     // e1 contribution
        partials[BN + n] = logf(detc);      // log det contribution
    }
}

// ---------------------------------------------------------------------------
// Single-block final reduction -> (e, e1, e2)
// ---------------------------------------------------------------------------
__global__ __launch_bounds__(1024) void gn_reduce_kernel(
    const float* __restrict__ partials, float* __restrict__ out)
{
    float s1 = 0.0f, s2 = 0.0f;
    for (int i = threadIdx.x; i < BN; i += 1024) {
        s1 += partials[i];
        s2 += partials[BN + i];
    }
    #pragma unroll
    for (int off = 32; off > 0; off >>= 1) {
        s1 += __shfl_down(s1, off);
        s2 += __shfl_down(s2, off);
    }
    __shared__ float l1[16], l2[16];
    const int w = threadIdx.x >> 6;
    if ((threadIdx.x & 63) == 0) { l1[w] = s1; l2[w] = s2; }
    __syncthreads();
    if (threadIdx.x == 0) {
        float e1 = 0.0f, sl = 0.0f;
        #pragma unroll
        for (int i = 0; i < 16; ++i) { e1 += l1[i]; sl += l2[i]; }
        const float e2 = (float)BN * LOG_2PI - 0.5f * sl;
        out[0] = e1 + (2.0f / 7.0f) * e2;  // e
        out[1] = e1;
        out[2] = e2;
    }
}

extern "C" void kernel_launch(void* const* d_in, const int* in_sizes, int n_in,
                              void* d_out, int out_size, void* d_ws, size_t ws_size,
                              hipStream_t stream) {
    const float* fb    = (const float*)d_in[0];
    const float* f_t   = (const float*)d_in[1];
    const float* ub    = (const float*)d_in[2];
    const float* noise = (const float*)d_in[3];
    float* out = (float*)d_out;
    float* wsf = (float*)d_ws;
    float* fbT      = wsf;                 // 128 MiB NHWC copy of fb
    float* partials = wsf + FBT_ELEMS;     // 2 * B*N floats

    transpose_nchw_nhwc<<<Bq * (HWq / 64) * (Cq / 64), 256, 0, stream>>>(fb, fbT);
    gn_sample_nhwc<<<BN / 4, 256, 0, stream>>>(fbT, f_t, ub, noise, partials);
    gn_reduce_kernel<<<1, 1024, 0, stream>>>(partials, out);
}